// Round 17
// baseline (430.736 us; speedup 1.0000x reference)
//
#include <hip/hip_runtime.h>
#include <hip/hip_bf16.h>
#include <math.h>

// Problem constants
#define DDIM   300
#define PFN    12
#define LFN    8
#define ICH    21      // PF + LF + 1
#define TPB    1024    // 16 waves/block; 4 lanes per sample
#define SPB    256     // samples per block -> grid = 256 = 1 block/CU EXACTLY
#define SLOT_DW 108    // per-sample feature slot: 9 positions * 12 dwords (16B-aligned)
#define W1Q    2160    // 20 oc * 9 taps * 12 icp-slots bf16-pair dwords (8640 B)
#define W2P    1200    // 30*20*2 bf16 tap-pair dwords (4800 B)
#define FW1P   2400    // 120 rows * 20 dw (19 data + 1 pad) (9600 B)
#define FW2P   6720    // 84 rows * 4 chunks * 20 dw (15 data + 5 pad) (26880 B)

__device__ __forceinline__ float lrelu(float v) { return v > 0.0f ? v : 0.2f * v; }

__device__ __forceinline__ unsigned int pack2(float a, float b) {
    union { __hip_bfloat162 h; unsigned int u; } cv;
    cv.h.x = __float2bfloat16(a);
    cv.h.y = __float2bfloat16(b);
    return cv.u;
}
__device__ __forceinline__ float bflo(unsigned int u) {
    union { unsigned int i; float f; } c; c.i = u << 16; return c.f;
}
__device__ __forceinline__ float bfhi(unsigned int u) {
    union { unsigned int i; float f; } c; c.i = u & 0xffff0000u; return c.f;
}

// Packed bf16 dot-2 with f32 accumulate: d = a.lo*b.lo + a.hi*b.hi + c.
__device__ __forceinline__ float dot2bf(unsigned int a, unsigned int b, float c) {
    float d;
    asm("v_dot2_f32_bf16 %0, %1, %2, %3" : "=v"(d) : "v"(a), "v"(b), "v"(c));
    return d;
}

// r16 post-mortem: fc2 b128 conversion WON at 4 waves/SIMD (430.6 bench, best;
// null at 2 waves/EU in r11 — regime-gated). VGPR=56 -> 70+ regs headroom.
// This round finishes the wide-DS conversion (bank-checked):
//  - feat slots 11->12 dw: conv1 features 99 b32 -> 27 b128 (2-way = free)
//  - w1 as [oc][tap][12 icp]: weights 495 b32 -> 135 b128 ({0,28,24,20} banks)
//  - fc1 [120][20] dw rows: 570 b32 -> 90 b128 + ~150 b32 ({0,24,16,8} banks)
//  - conv2 bf16 dot2 (r12 layout, uint2 reads) + biases from global to pay
//    the feat pad: LDS = 160,512B <= 161,792 proven-usable, still 1 block/CU.
// DS issues/wave ~1880 -> ~990.
__launch_bounds__(TPB, 2)
__global__ void disc_kernel(
    const int* __restrict__ state, const int* __restrict__ des,
    const int* __restrict__ act,
    const int* __restrict__ asp_g,   // action_state_pad (S,9)
    const int* __restrict__ pmp_g,   // policy_mask_pad  (S,9)
    const float* __restrict__ path_feature,  // (S,D,12)
    const float* __restrict__ link_feature,  // (S,8)
    const float* __restrict__ w1, const float* __restrict__ b1,   // conv1 (20,21,3,3)
    const float* __restrict__ w2, const float* __restrict__ b2,   // conv2 (30,20,2,2)
    const float* __restrict__ fw1, const float* __restrict__ fb1, // (120,38)
    const float* __restrict__ fw2, const float* __restrict__ fb2, // (84,120)
    const float* __restrict__ fw3, const float* __restrict__ fb3, // (1,84)
    float* __restrict__ out, int n)
{
    __shared__ __align__(16) unsigned int w1q[W1Q];   //   8640 B
    __shared__ __align__(16) unsigned int w2p[W2P];   //   4800 B
    __shared__ __align__(16) unsigned int fw1h[FW1P]; //   9600 B
    __shared__ __align__(16) unsigned int fw2h[FW2P]; //  26880 B
    __shared__ __align__(16) unsigned int feat[SPB * SLOT_DW]; // 110592 B => 160512 B

    const int tid = threadIdx.x;

    // ---- Stage all weights to LDS once per block (= once per CU).
    {
        // conv1: w1q[oc][t][icp(12)] = pack2(w1[oc][2icp][t], w1[oc][2icp+1][t]);
        // icp==10 pairs ic20 with 0; icp==11 = 0 pad.
        for (int i = tid; i < W1Q; i += TPB) {
            const int oc = i / 108, r = i % 108, t = r / 12, icp = r % 12;
            unsigned int v = 0u;
            if (icp < 11) {
                const float lo = w1[(oc * ICH + 2 * icp) * 9 + t];
                const float hi = (icp < 10) ? w1[(oc * ICH + 2 * icp + 1) * 9 + t] : 0.0f;
                v = pack2(lo, hi);
            }
            w1q[i] = v;
        }
        // conv2: w2p[j][oc][h] = pack2(w2[j][oc][2h], w2[j][oc][2h+1])
        for (int i = tid; i < W2P; i += TPB) {
            const int j = i / 40, r = i % 40, oc = r / 2, h = r % 2;
            w2p[i] = pack2(w2[j * 80 + oc * 4 + 2 * h], w2[j * 80 + oc * 4 + 2 * h + 1]);
        }
        // fc1: fw1h[row][0..18] packed pairs, [19] pad
        for (int i = tid; i < FW1P; i += TPB) {
            const int row = i / 20, col = i % 20;
            unsigned int v = 0u;
            if (col < 19) v = pack2(fw1[row * 38 + 2 * col], fw1[row * 38 + 2 * col + 1]);
            fw1h[i] = v;
        }
        // fc2: fw2h[row][ch(4) @ 20 dw][m(20)]; m<15 = pack2(...)
        for (int i = tid; i < FW2P; i += TPB) {
            const int row = i / 80, c = i % 80, ch = c / 20, m = c % 20;
            unsigned int v = 0u;
            if (m < 15) v = pack2(fw2[row * 120 + ch * 30 + 2 * m],
                                  fw2[row * 120 + ch * 30 + 2 * m + 1]);
            fw2h[i] = v;
        }
    }
    __syncthreads();

    const int lane4  = tid & 3;       // lane within sample quad
    const int lsamp  = tid >> 2;      // sample within block
    const int sample = blockIdx.x * SPB + lsamp;
    if (sample >= n) return;

    const int s  = state[sample];
    const int d  = des[sample];
    const int ai = act[sample];

    const int* asp = asp_g + s * 9;
    const int* pmp = pmp_g + s * 9;
    unsigned int* fslot = feat + lsamp * SLOT_DW;

    // ---- Cooperative gather: lane k handles positions k, k+4, k+8.
    // NEW_INDEX packed as nibbles: p -> {7,0,1,6,8,2,5,4,3}
#pragma unroll
    for (int t = 0; t < 3; ++t) {
        const int p = lane4 + 4 * t;
        if (p < 9) {
            const int a  = (int)((0x345286107ULL >> (4 * p)) & 0xF);
            const int na = asp[a];
            const float m = (float)pmp[a];
            const float4* pf = (const float4*)(path_feature + (na * DDIM + d) * PFN);
            const float4 v0 = pf[0], v1 = pf[1], v2 = pf[2];
            const float4* lf = (const float4*)(link_feature + na * LFN);
            const float4 u0 = lf[0], u1 = lf[1];
            unsigned int* dst = fslot + p * 12;   // 12-dw slot (dword 11 = unused pad)
            dst[0] = pack2(v0.x, v0.y); dst[1] = pack2(v0.z, v0.w);
            dst[2] = pack2(v1.x, v1.y); dst[3] = pack2(v1.z, v1.w);
            dst[4] = pack2(v2.x, v2.y); dst[5] = pack2(v2.z, v2.w);
            dst[6] = pack2(u0.x, u0.y); dst[7] = pack2(u0.z, u0.w);
            dst[8] = pack2(u1.x, u1.y); dst[9] = pack2(u1.z, u1.w);
            dst[10] = pack2(m, 0.0f);             // channel 20 = mask, high half = pad
        }
    }
    // Quad writes its own slot; quads never cross a wave boundary, so
    // draining our wave's ds_writes orders the cross-lane reads.
    asm volatile("s_waitcnt lgkmcnt(0)" ::: "memory");

    // ---- conv1: lane k computes output channels [5k, 5k+5).
    // Per icp-group g: 9 feature b128s (4 ic-pairs x 9 positions) and one
    // weight b128 per (oc,tap). icp 11 is pad: read but never used (g==2
    // processes only 3 ic-pairs).
    const int oc0 = lane4 * 5;
    float o[5][9];
#pragma unroll
    for (int c = 0; c < 5; ++c) {
        const float bb = b1[oc0 + c];
#pragma unroll
        for (int q = 0; q < 9; ++q) o[c][q] = bb;
    }

#pragma unroll
    for (int g = 0; g < 3; ++g) {
        uint4 f4[9];
#pragma unroll
        for (int q = 0; q < 9; ++q)
            f4[q] = *(const uint4*)(fslot + q * 12 + 4 * g);
#pragma unroll
        for (int c = 0; c < 5; ++c) {
            const uint4* wrow = (const uint4*)(w1q + (oc0 + c) * 108) + g;
#pragma unroll
            for (int t = 0; t < 9; ++t) {
                const uint4 w4 = wrow[t * 3];
                const int ky = t / 3 - 1, kx = t % 3 - 1;
#pragma unroll
                for (int ic = 0; ic < 4; ++ic) {
                    if (g == 2 && ic == 3) continue;   // icp 11 = pad
                    const unsigned int wv =
                        (ic == 0) ? w4.x : (ic == 1) ? w4.y : (ic == 2) ? w4.z : w4.w;
#pragma unroll
                    for (int y = 0; y < 3; ++y) {
                        const int iy = y + ky;
                        if (iy < 0 || iy > 2) continue;
#pragma unroll
                        for (int x = 0; x < 3; ++x) {
                            const int ix = x + kx;
                            if (ix < 0 || ix > 2) continue;
                            const uint4 fq = f4[iy * 3 + ix];
                            const unsigned int fv =
                                (ic == 0) ? fq.x : (ic == 1) ? fq.y : (ic == 2) ? fq.z : fq.w;
                            o[c][y * 3 + x] = dot2bf(wv, fv, o[c][y * 3 + x]);
                        }
                    }
                }
            }
        }
    }

    // ---- lrelu + 2x2 maxpool (stride 1), pack to bf16 pairs for conv2 dot2.
    unsigned int pp[5][2];
#pragma unroll
    for (int c = 0; c < 5; ++c) {
        float v[9];
#pragma unroll
        for (int q = 0; q < 9; ++q) v[q] = lrelu(o[c][q]);
        const float p0 = fmaxf(fmaxf(v[0], v[1]), fmaxf(v[3], v[4]));
        const float p1 = fmaxf(fmaxf(v[1], v[2]), fmaxf(v[4], v[5]));
        const float p2 = fmaxf(fmaxf(v[3], v[4]), fmaxf(v[6], v[7]));
        const float p3 = fmaxf(fmaxf(v[4], v[5]), fmaxf(v[7], v[8]));
        pp[c][0] = pack2(p0, p1);
        pp[c][1] = pack2(p2, p3);
    }

    // ---- conv2 (2x2 VALID) via dot2 over tap-pairs (uint2 LDS reads; quad
    // offsets {0,10,20,30} dw -> disjoint banks), butterfly reduce.
    float x30[30];
#pragma unroll
    for (int j = 0; j < 30; ++j) {
        const uint2* wb = (const uint2*)(w2p + j * 40 + oc0 * 2);
        float acc = 0.0f;
#pragma unroll
        for (int c = 0; c < 5; ++c) {
            const uint2 w = wb[c];
            acc = dot2bf(w.x, pp[c][0], acc);
            acc = dot2bf(w.y, pp[c][1], acc);
        }
        acc += __shfl_xor(acc, 1, 64);
        acc += __shfl_xor(acc, 2, 64);
        x30[j] = lrelu(acc + b2[j]);
    }

    // Pack x30 once to bf16 pairs for the dot2 FC path.
    unsigned int xp[15];
#pragma unroll
    for (int m = 0; m < 15; ++m) xp[m] = pack2(x30[2 * m], x30[2 * m + 1]);

    // ---- fc1 (38->120): lane k computes rows [30k, 30k+30); 3x b128 + 3x b32
    // per 20-dw row (quad row starts {0,24,16,8} banks -> conflict-free).
    float h1[30];
    const int j0 = lane4 * 30;
    const int ohd   = (30 + ai) >> 1;  // one-hot dword within row (15..18)
    const int ohodd = (30 + ai) & 1;   // which bf16 half
#pragma unroll
    for (int jj = 0; jj < 30; ++jj) {
        const unsigned int* wr = fw1h + (j0 + jj) * 20;      // 80B-aligned
        const uint4* w4p = (const uint4*)wr;
        const uint4 a0 = w4p[0], a1 = w4p[1], a2 = w4p[2];
        const unsigned int w12 = wr[12], w13 = wr[13], w14 = wr[14];
        const unsigned int uoh = wr[ohd];                    // dynamic b32
        float acc = fb1[j0 + jj] + (ohodd ? bfhi(uoh) : bflo(uoh));
        const unsigned int wv[15] = {a0.x, a0.y, a0.z, a0.w, a1.x, a1.y, a1.z, a1.w,
                                     a2.x, a2.y, a2.z, a2.w, w12, w13, w14};
#pragma unroll
        for (int m = 0; m < 15; ++m)
            acc = dot2bf(wv[m], xp[m], acc);
        h1[jj] = lrelu(acc);
    }

    // Pack h1 once to bf16 pairs.
    unsigned int hp[15];
#pragma unroll
    for (int m = 0; m < 15; ++m) hp[m] = pack2(h1[2 * m], h1[2 * m + 1]);

    // ---- fc2 (120->84) + fc3 (84->1): 4x conflict-free ds_read_b128 per
    // output (20-dw staggered chunks, banks {0,20,8,28}), dual-chain dot2,
    // butterfly reduce, fold straight into fc3.
    float z = fb3[0];
#pragma unroll 2
    for (int i = 0; i < 84; ++i) {
        const uint4* w4 = (const uint4*)(fw2h + i * 80 + lane4 * 20);  // 80B-aligned
        const uint4 a0 = w4[0], a1 = w4[1], a2 = w4[2], a3 = w4[3];
        float alo = 0.0f, ahi = 0.0f;
        alo = dot2bf(a0.x, hp[0],  alo);  ahi = dot2bf(a2.x, hp[8],  ahi);
        alo = dot2bf(a0.y, hp[1],  alo);  ahi = dot2bf(a2.y, hp[9],  ahi);
        alo = dot2bf(a0.z, hp[2],  alo);  ahi = dot2bf(a2.z, hp[10], ahi);
        alo = dot2bf(a0.w, hp[3],  alo);  ahi = dot2bf(a2.w, hp[11], ahi);
        alo = dot2bf(a1.x, hp[4],  alo);  ahi = dot2bf(a3.x, hp[12], ahi);
        alo = dot2bf(a1.y, hp[5],  alo);  ahi = dot2bf(a3.y, hp[13], ahi);
        alo = dot2bf(a1.z, hp[6],  alo);  ahi = dot2bf(a3.z, hp[14], ahi);
        alo = dot2bf(a1.w, hp[7],  alo);
        float a = alo + ahi;
        a += __shfl_xor(a, 1, 64);
        a += __shfl_xor(a, 2, 64);
        z = fmaf(fw3[i], lrelu(a + fb2[i]), z);
    }

    if (lane4 == 0)
        out[sample] = 1.0f / (1.0f + __expf(-z));
}

extern "C" void kernel_launch(void* const* d_in, const int* in_sizes, int n_in,
                              void* d_out, int out_size, void* d_ws, size_t ws_size,
                              hipStream_t stream) {
    const int*   state = (const int*)d_in[0];
    const int*   des   = (const int*)d_in[1];
    const int*   act   = (const int*)d_in[2];
    const int*   asp   = (const int*)d_in[3];
    const int*   pmp   = (const int*)d_in[4];
    const float* pathf = (const float*)d_in[5];
    const float* linkf = (const float*)d_in[6];
    const float* w1    = (const float*)d_in[7];
    const float* b1    = (const float*)d_in[8];
    const float* w2    = (const float*)d_in[9];
    const float* b2    = (const float*)d_in[10];
    const float* fw1   = (const float*)d_in[11];
    const float* fb1   = (const float*)d_in[12];
    const float* fw2   = (const float*)d_in[13];
    const float* fb2   = (const float*)d_in[14];
    const float* fw3   = (const float*)d_in[15];
    const float* fb3   = (const float*)d_in[16];

    const int n = in_sizes[0];
    dim3 grid((n + SPB - 1) / SPB), block(TPB);
    hipLaunchKernelGGL(disc_kernel, grid, block, 0, stream,
                       state, des, act, asp, pmp, pathf, linkf,
                       w1, b1, w2, b2, fw1, fb1, fw2, fb2, fw3, fb3,
                       (float*)d_out, n);
}